// Round 7
// baseline (273.528 us; speedup 1.0000x reference)
//
#include <hip/hip_runtime.h>
#include <hip/hip_fp16.h>

#define NU 100000
#define NI 200000
#define NF 64
#define NE 1000000
#define NN 300000            // NU + NI
#define SCAN_CHUNK 1024
#define NBLK ((NN + SCAN_CHUNK - 1) / SCAN_CHUNK)   // 293

typedef float nfloat4 __attribute__((ext_vector_type(4)));   // native vec for nontemporal

// ---------- fp16 helpers (8 halves in a uint4) ----------
__device__ __forceinline__ void fma8(float sum[8], float v, uint4 q) {
    union { uint4 u; __half2 h[4]; } c; c.u = q;
    #pragma unroll
    for (int i = 0; i < 4; ++i) {
        float2 f = __half22float2(c.h[i]);
        sum[2 * i]     = fmaf(v, f.x, sum[2 * i]);
        sum[2 * i + 1] = fmaf(v, f.y, sum[2 * i + 1]);
    }
}
__device__ __forceinline__ uint4 pack8(const float sum[8]) {
    union { uint4 u; __half2 h[4]; } c;
    #pragma unroll
    for (int i = 0; i < 4; ++i)
        c.h[i] = __float22half2_rn(make_float2(sum[2 * i], sum[2 * i + 1]));
    return c.u;
}
__device__ __forceinline__ void add8(float4& a0, float4& a1, uint4 q) {
    union { uint4 u; __half2 h[4]; } c; c.u = q;
    float2 f0 = __half22float2(c.h[0]);
    float2 f1 = __half22float2(c.h[1]);
    float2 f2 = __half22float2(c.h[2]);
    float2 f3 = __half22float2(c.h[3]);
    a0.x += f0.x; a0.y += f0.y; a0.z += f1.x; a0.w += f1.y;
    a1.x += f2.x; a1.y += f2.y; a1.z += f3.x; a1.w += f3.y;
}

// ---------- 0. convert concat(user,item) fp32 -> fp16 table ----------
__global__ void f0_to_h(const float4* __restrict__ user4,
                        const float4* __restrict__ item4,
                        uint4* __restrict__ f0h) {
    int i = blockIdx.x * blockDim.x + threadIdx.x;      // one uint4 (8 feats) each
    if (i >= NN * 8) return;
    size_t fi = (size_t)i * 2;
    const size_t ub = (size_t)NU * 16;
    float4 a = (fi < ub) ? user4[fi] : item4[fi - ub];
    float4 b = (fi + 1 < ub) ? user4[fi + 1] : item4[fi + 1 - ub];
    float s[8] = { a.x, a.y, a.z, a.w, b.x, b.y, b.z, b.w };
    f0h[i] = pack8(s);
}

// ---------- 1. histogram ----------
__global__ void hist_kernel(const int* __restrict__ rows, int* __restrict__ counts) {
    int e = blockIdx.x * blockDim.x + threadIdx.x;
    if (e < NE) atomicAdd(&counts[rows[e]], 1);
}

// ---------- 2a. per-chunk exclusive scan ----------
__global__ void scan_blocks(const int* __restrict__ counts, int* __restrict__ starts,
                            int* __restrict__ bsums) {
    __shared__ int lds[256];
    int base = blockIdx.x * SCAN_CHUNK;
    int t = threadIdx.x;
    int v[4]; int s = 0;
    #pragma unroll
    for (int j = 0; j < 4; ++j) {
        int idx = base + t * 4 + j;
        v[j] = (idx < NN) ? counts[idx] : 0;
        s += v[j];
    }
    lds[t] = s; __syncthreads();
    for (int off = 1; off < 256; off <<= 1) {
        int x = lds[t];
        int y = (t >= off) ? lds[t - off] : 0;
        __syncthreads();
        lds[t] = x + y;
        __syncthreads();
    }
    if (t == 255) bsums[blockIdx.x] = lds[255];
    int run = (t > 0) ? lds[t - 1] : 0;
    #pragma unroll
    for (int j = 0; j < 4; ++j) {
        int idx = base + t * 4 + j;
        if (idx < NN) starts[idx] = run;
        run += v[j];
    }
}

// ---------- 2b. scan block sums ----------
__global__ void scan_sums(int* __restrict__ bsums) {
    __shared__ int lds[512];
    int t = threadIdx.x;
    lds[t] = (t < NBLK) ? bsums[t] : 0;
    __syncthreads();
    for (int off = 1; off < 512; off <<= 1) {
        int x = lds[t];
        int y = (t >= off) ? lds[t - off] : 0;
        __syncthreads();
        lds[t] = x + y;
        __syncthreads();
    }
    if (t < NBLK) bsums[t] = (t > 0) ? lds[t - 1] : 0;
}

// ---------- 2c. add offsets; cursor = start ----------
__global__ void scan_add(int* __restrict__ starts, const int* __restrict__ bsums,
                         int* __restrict__ cursor) {
    int i = blockIdx.x * blockDim.x + threadIdx.x;
    if (i >= NN) return;
    int s = starts[i] + bsums[i / SCAN_CHUNK];
    starts[i] = s;
    cursor[i] = s;
}

// ---------- 3. scatter (col,val) into CSR order via TCC-side atomicExch ----------
__global__ void scatter_kernel(const int* __restrict__ rows, const int* __restrict__ cols,
                               const float* __restrict__ vals, int* __restrict__ cursor,
                               unsigned long long* __restrict__ edges) {
    int e = blockIdx.x * blockDim.x + threadIdx.x;
    if (e >= NE) return;
    int r = rows[e];
    int p = atomicAdd(&cursor[r], 1);
    unsigned long long rec = (unsigned long long)(unsigned)cols[e] |
                             ((unsigned long long)(unsigned)__float_as_uint(vals[e]) << 32);
    // fire-and-forget: record lands at the home TCC, no local L2 line acquisition
    atomicExch(&edges[p], rec);
}

// ---------- 4. SpMM: 8 lanes/row, 2 independent gathers in flight ----------
// MODE 0/1: write fout (fp16 table) only.
// MODE 2:   acc = base(fp32) + f1 + f2 + sum   (no fout)
template <int MODE>
__global__ void spmm_row8(const int* __restrict__ starts, const int* __restrict__ ends,
                          const int2* __restrict__ edges, const uint4* __restrict__ gtab,
                          uint4* __restrict__ fout,
                          const uint4* __restrict__ f1h, const uint4* __restrict__ f2h,
                          const float4* __restrict__ user4, const float4* __restrict__ item4,
                          float4* __restrict__ acc) {
    int tid = blockIdx.x * blockDim.x + threadIdx.x;
    int row = tid >> 3;          // 8 rows per wave
    if (row >= NN) return;
    int j = tid & 7;             // which 16B chunk (8 feats) of the row
    int s = starts[row];
    int e = ends[row];
    float sum[8];
    #pragma unroll
    for (int t = 0; t < 8; ++t) sum[t] = 0.f;

    int k = s;
    int2 ed0, ed1;
    if (k < e)     ed0 = edges[k];
    if (k + 1 < e) ed1 = edges[k + 1];
    while (k < e) {
        int2 c0 = ed0;
        int2 c1 = ed1;
        bool h1 = (k + 1 < e);
        int kn = k + 2;
        if (kn < e)     ed0 = edges[kn];        // prefetch next pair
        if (kn + 1 < e) ed1 = edges[kn + 1];
        uint4 q0 = gtab[(size_t)c0.x * 8 + j];  // two independent 128B gathers
        uint4 q1;
        if (h1) q1 = gtab[(size_t)c1.x * 8 + j];
        fma8(sum, __int_as_float(c0.y), q0);
        if (h1) fma8(sum, __int_as_float(c1.y), q1);
        k = kn;
    }

    if (MODE != 2) {
        fout[(size_t)row * 8 + j] = pack8(sum);
    } else {
        size_t r16 = (size_t)row * 16 + (size_t)j * 2;
        float4 a0, a1;
        if (row < NU) { a0 = user4[r16]; a1 = user4[r16 + 1]; }
        else {
            size_t bi = r16 - (size_t)NU * 16;
            a0 = item4[bi]; a1 = item4[bi + 1];
        }
        a0.x += sum[0]; a0.y += sum[1]; a0.z += sum[2]; a0.w += sum[3];
        a1.x += sum[4]; a1.y += sum[5]; a1.z += sum[6]; a1.w += sum[7];
        size_t t8 = (size_t)row * 8 + j;
        add8(a0, a1, f1h[t8]);
        add8(a0, a1, f2h[t8]);
        nfloat4 n0 = { a0.x, a0.y, a0.z, a0.w };
        nfloat4 n1 = { a1.x, a1.y, a1.z, a1.w };
        __builtin_nontemporal_store(n0, (nfloat4*)&acc[r16]);      // write-only stream
        __builtin_nontemporal_store(n1, (nfloat4*)&acc[r16 + 1]);
    }
}

extern "C" void kernel_launch(void* const* d_in, const int* in_sizes, int n_in,
                              void* d_out, int out_size, void* d_ws, size_t ws_size,
                              hipStream_t stream) {
    const float* user = (const float*)d_in[0];
    const float* item = (const float*)d_in[1];
    const int*   rows = (const int*)d_in[2];
    const int*   cols = (const int*)d_in[3];
    const float* vals = (const float*)d_in[4];
    float* acc = (float*)d_out;

    const size_t TB = (size_t)NN * 8 * sizeof(uint4);    // fp16 table: 38.4 MB
    char* w = (char*)d_ws;
    uint4* f0h    = (uint4*)(w);
    uint4* f1h    = (uint4*)(w + TB);
    uint4* f2h    = (uint4*)(w + 2 * TB);
    unsigned long long* edges = (unsigned long long*)(w + 3 * TB);
    int*   starts = (int*)  (w + 3 * TB + (size_t)NE * 8);
    int*   cursor = (int*)  (w + 3 * TB + (size_t)NE * 8 + (size_t)NN * 4);
    int*   bsums  = (int*)  (w + 3 * TB + (size_t)NE * 8 + (size_t)NN * 8);

    const int blocksE = (NE + 255) / 256;        // 3907
    const int blocksN = (NN + 255) / 256;        // 1172
    const int blocksC = (NN * 8 + 255) / 256;    // 9375
    const int blocksR = (NN * 8 + 255) / 256;    // 9375  (8 lanes/row)

    // CSR build + fp16 base table
    (void)hipMemsetAsync(cursor, 0, (size_t)NN * 4, stream);
    hist_kernel<<<blocksE, 256, 0, stream>>>(rows, cursor);
    scan_blocks<<<NBLK, 256, 0, stream>>>(cursor, starts, bsums);
    scan_sums<<<1, 512, 0, stream>>>(bsums);
    scan_add<<<blocksN, 256, 0, stream>>>(starts, bsums, cursor);
    scatter_kernel<<<blocksE, 256, 0, stream>>>(rows, cols, vals, cursor, edges);
    f0_to_h<<<blocksC, 256, 0, stream>>>((const float4*)user, (const float4*)item, f0h);

    // 3 SpMM layers (cursor holds row ends); acc only touched in layer 3
    spmm_row8<0><<<blocksR, 256, 0, stream>>>(starts, cursor, (const int2*)edges, f0h,
                                              f1h, nullptr, nullptr,
                                              nullptr, nullptr, nullptr);
    spmm_row8<1><<<blocksR, 256, 0, stream>>>(starts, cursor, (const int2*)edges, f1h,
                                              f2h, nullptr, nullptr,
                                              nullptr, nullptr, nullptr);
    spmm_row8<2><<<blocksR, 256, 0, stream>>>(starts, cursor, (const int2*)edges, f2h,
                                              nullptr, f1h, f2h,
                                              (const float4*)user, (const float4*)item,
                                              (float4*)acc);
}